// Round 4
// baseline (148.920 us; speedup 1.0000x reference)
//
#include <hip/hip_runtime.h>

#define W 512
#define PLANE (W * W)            // 262144
#define NPTS (32 * PLANE)        // 8388608 spatial points per channel
#define SEG 8                    // rows marched per wave
#define NBLK 1024                // 4096 waves = 32 batches * 64 segs * 2 halves

static constexpr float DT_INV = 100.0f;   // 1/DT
static constexpr float NU_C   = 0.001f;
// DX = 1.0 -> grad scale 0.5, laplacian scale 1.0

// v8 (rerun; round-3 bench was an infra failure, no data came back):
// SEG=8 rolling march, depth-2 software pipeline.
// Wave = (batch, 8-row segment, 256-col half). Each lane owns one float4
// column slice and marches 8 rows keeping u/v rows y-1,y,y+1 in registers.
// All loads (u,v rows; prev rows; x-edge scalars) are issued TWO compute
// steps before first use, so each vmcnt wait has ~2x500 cy of slack plus
// 4-wave/SIMD interleave. u_pred re-read factor 10/8 = 1.25x -> logical
// traffic ~151 MB (vs 168 in v7, 268 in v6). x-neighbors inside the wave
// via width-64 shuffles; the two columns outside the wave (col cb-1,
// col cb+256) come from uniform-address scalar loads, also prefetched.
__global__ __launch_bounds__(256, 4) void ns_loss_v8(
    const float* __restrict__ u_pred,
    const float* __restrict__ u_prev,
    float* __restrict__ partial)
{
    __shared__ float red[16];               // end-reduction only

    const int t  = threadIdx.x;
    const int l  = t & 63;
    const int wv = t >> 6;

    // bijective XCD swizzle (1024 % 8 == 0)
    const int bid = blockIdx.x;
    const int lid = ((bid & 7) << 7) | (bid >> 3);

    const int gw   = (lid << 2) | wv;       // global wave 0..4095
    const int b    = gw >> 7;               // batch 0..31
    const int rem  = gw & 127;
    const int seg  = rem >> 1;              // 0..63
    const int half = rem & 1;
    const int y0   = seg << 3;              // segment base row
    const int cb   = half << 8;             // column-half base (0 or 256)
    const int c0   = cb + (l << 2);         // this lane's quad base col
    const int cL   = (cb + 511) & 511;      // col left of the half
    const int cR   = (cb + 256) & 511;      // col right of the half

    const float* u0 = u_pred + (size_t)b * (2 * PLANE);
    const float* v0 = u0 + PLANE;
    const float* q0 = u_prev + (size_t)b * (2 * PLANE);
    const float* q1 = q0 + PLANE;

    // Au[i]/Av[i] = row (y0 + i - 1) mod 512; Apu/Apv[i] = prev row y0+i.
    // All indices compile-time constant under full unroll (stay in VGPRs).
    float4 Au[SEG + 2], Av[SEG + 2], Apu[SEG], Apv[SEG];
    float  eLu[SEG], eRu[SEG], eLv[SEG], eRv[SEG];

    // ---- prologue: fill pipeline 2 steps deep ----
#pragma unroll
    for (int i = 0; i < 4; ++i) {
        const int y = (y0 + i - 1) & 511;
        Au[i] = *(const float4*)(u0 + y * W + c0);
        Av[i] = *(const float4*)(v0 + y * W + c0);
    }
#pragma unroll
    for (int i = 0; i < 2; ++i) {
        const int y = y0 + i;               // <= 511, no wrap
        Apu[i] = *(const float4*)(q0 + y * W + c0);
        Apv[i] = *(const float4*)(q1 + y * W + c0);
        eLu[i] = u0[y * W + cL];  eRu[i] = u0[y * W + cR];
        eLv[i] = v0[y * W + cL];  eRv[i] = v0[y * W + cR];
    }

    float s_pde = 0.0f, s_div = 0.0f;

#pragma unroll
    for (int k = 0; k < SEG; ++k) {
        // ---- issue loads for step k+2 (2 compute steps of slack) ----
        if (k + 4 <= SEG + 1) {
            const int y = (y0 + k + 3) & 511;   // row for Au[k+4]
            Au[k + 4] = *(const float4*)(u0 + y * W + c0);
            Av[k + 4] = *(const float4*)(v0 + y * W + c0);
        }
        if (k + 2 <= SEG - 1) {
            const int y = y0 + k + 2;           // <= 511, no wrap
            Apu[k + 2] = *(const float4*)(q0 + y * W + c0);
            Apv[k + 2] = *(const float4*)(q1 + y * W + c0);
            eLu[k + 2] = u0[y * W + cL];  eRu[k + 2] = u0[y * W + cR];
            eLv[k + 2] = v0[y * W + cL];  eRv[k + 2] = v0[y * W + cR];
        }

        // ---- compute row y0+k from the register window ----
        const float4 um4 = Au[k], uc4 = Au[k + 1], up4 = Au[k + 2];
        const float4 vm4 = Av[k], vc4 = Av[k + 1], vp4 = Av[k + 2];
        const float4 pu4 = Apu[k], pv4 = Apv[k];

        const float uLs = __shfl(uc4.w, (l + 63) & 63, 64);
        const float uRs = __shfl(uc4.x, (l + 1) & 63, 64);
        const float vLs = __shfl(vc4.w, (l + 63) & 63, 64);
        const float vRs = __shfl(vc4.x, (l + 1) & 63, 64);
        const float uL = (l == 0)  ? eLu[k] : uLs;
        const float uR = (l == 63) ? eRu[k] : uRs;
        const float vL = (l == 0)  ? eLv[k] : vLs;
        const float vR = (l == 63) ? eRv[k] : vRs;

        const float ua[6]  = {uL, uc4.x, uc4.y, uc4.z, uc4.w, uR};
        const float va[6]  = {vL, vc4.x, vc4.y, vc4.z, vc4.w, vR};
        const float umA[4] = {um4.x, um4.y, um4.z, um4.w};
        const float upA[4] = {up4.x, up4.y, up4.z, up4.w};
        const float vmA[4] = {vm4.x, vm4.y, vm4.z, vm4.w};
        const float vpA[4] = {vp4.x, vp4.y, vp4.z, vp4.w};
        const float puA[4] = {pu4.x, pu4.y, pu4.z, pu4.w};
        const float pvA[4] = {pv4.x, pv4.y, pv4.z, pv4.w};

#pragma unroll
        for (int j = 0; j < 4; ++j) {
            const float u   = ua[j + 1];
            const float v   = va[j + 1];
            const float u_x = (ua[j + 2] - ua[j]) * 0.5f;
            const float v_x = (va[j + 2] - va[j]) * 0.5f;
            const float u_y = (upA[j] - umA[j]) * 0.5f;
            const float v_y = (vpA[j] - vmA[j]) * 0.5f;
            const float lap_u = upA[j] + umA[j] + ua[j + 2] + ua[j] - 4.0f * u;
            const float lap_v = vpA[j] + vmA[j] + va[j + 2] + va[j] - 4.0f * v;
            const float rx = (u - puA[j]) * DT_INV + u * u_x + v * u_y - NU_C * lap_u;
            const float ry = (v - pvA[j]) * DT_INV + u * v_x + v * v_y - NU_C * lap_v;
            const float dv = u_x + v_y;
            s_pde += rx * rx + ry * ry;
            s_div += dv * dv;
        }
    }

    // ---- reduction ----
#pragma unroll
    for (int off = 32; off > 0; off >>= 1) {
        s_pde += __shfl_down(s_pde, off);
        s_div += __shfl_down(s_div, off);
    }

    if (l == 0) { red[wv] = s_pde; red[8 + wv] = s_div; }
    __syncthreads();
    if (t == 0) {
        partial[lid]        = red[0] + red[1] + red[2] + red[3];
        partial[NBLK + lid] = red[8] + red[9] + red[10] + red[11];
    }
}

__global__ __launch_bounds__(256) void ns_reduce(
    const float* __restrict__ partial,
    float* __restrict__ out)
{
    double sp = 0.0, sd = 0.0;
    for (int i = threadIdx.x; i < NBLK; i += 256) {
        sp += (double)partial[i];
        sd += (double)partial[NBLK + i];
    }
#pragma unroll
    for (int off = 32; off > 0; off >>= 1) {
        sp += __shfl_down(sp, off);
        sd += __shfl_down(sd, off);
    }
    __shared__ double ssp[4], ssd[4];
    const int lane = threadIdx.x & 63;
    const int wv   = threadIdx.x >> 6;
    if (lane == 0) { ssp[wv] = sp; ssd[wv] = sd; }
    __syncthreads();
    if (threadIdx.x == 0) {
        const double tp = ssp[0] + ssp[1] + ssp[2] + ssp[3];
        const double td = ssd[0] + ssd[1] + ssd[2] + ssd[3];
        const double inv = 1.0 / (double)NPTS;
        const double pde = tp * inv;
        const double dvl = td * inv;
        out[0] = (float)(pde + 0.1 * dvl);
        out[1] = (float)pde;
        out[2] = (float)dvl;
    }
}

extern "C" void kernel_launch(void* const* d_in, const int* in_sizes, int n_in,
                              void* d_out, int out_size, void* d_ws, size_t ws_size,
                              hipStream_t stream) {
    const float* u_pred = (const float*)d_in[0];
    const float* u_prev = (const float*)d_in[1];
    float* out = (float*)d_out;
    float* partial = (float*)d_ws;   // 2*NBLK floats = 8 KB

    ns_loss_v8<<<NBLK, 256, 0, stream>>>(u_pred, u_prev, partial);
    ns_reduce<<<1, 256, 0, stream>>>(partial, out);
}